// Round 1
// baseline (133.601 us; speedup 1.0000x reference)
//
#include <hip/hip_runtime.h>

#define DIM 128
#define NROWS 2048

typedef float v2f __attribute__((ext_vector_type(2)));

// ---------------------------------------------------------------------------
// prep: hiT[d][n]  = sum_k z_i[n][k] * W1[k][d]            (d-major, transposed)
//       hjbT[d][m] = b1[d] + sum_k z_j[m][k] * W1[128+k][d]
// 256 blocks x 256 threads; block b handles 16 rows of one side.
// ---------------------------------------------------------------------------
__global__ __launch_bounds__(256) void prep_kernel(
    const float* __restrict__ z_i, const float* __restrict__ z_j,
    const float* __restrict__ W1, const float* __restrict__ b1,
    float* __restrict__ hiT, float* __restrict__ hjbT) {
  __shared__ float zs[16 * DIM];  // 8 KB

  const int b = blockIdx.x;            // 0..255
  const bool side = (b >= 128);        // false: hi, true: hjb
  const int rowbase = (side ? (b - 128) : b) * 16;
  const float* src = side ? z_j : z_i;

  const int t = threadIdx.x;
  // stage 16 z-rows (2048 floats) coalesced
  const float4* s4 = (const float4*)(src + rowbase * DIM);
  float4* z4 = (float4*)zs;
  z4[t] = s4[t];
  z4[t + 256] = s4[t + 256];
  __syncthreads();

  const int d = t & 127;
  const int half = t >> 7;  // wave-uniform (0 for waves 0-1, 1 for waves 2-3)
  const float* w = W1 + (side ? DIM * DIM : 0) + d;
  const float* zrow = zs + (half * 8) * DIM;

  float acc[8];
#pragma unroll
  for (int r = 0; r < 8; ++r) acc[r] = 0.f;

#pragma unroll 4
  for (int k = 0; k < DIM; ++k) {
    const float wv = w[k * DIM];  // coalesced across lanes (d consecutive)
#pragma unroll
    for (int r = 0; r < 8; ++r)
      acc[r] = fmaf(zrow[r * DIM + k], wv, acc[r]);  // LDS broadcast
  }

  const float bias = side ? b1[d] : 0.f;
  float* dst = (side ? hjbT : hiT) + d * NROWS + rowbase + half * 8;
#pragma unroll
  for (int r = 0; r < 8; ++r) dst[r] = acc[r] + bias;
}

// ---------------------------------------------------------------------------
// main: out[i][j] = b2 + sum_d relu(hiT[d][i] + hjbT[d][j]) * W2[d]
// grid (16,16), 256 threads, 128x128 tile per block, 8x8 per thread.
// d staged to LDS in chunks of 32, [d][row] layout (conflict-free b128 reads).
// Packed-fp32 over the j dimension (v_pk_add/max/fma_f32).
// ---------------------------------------------------------------------------
__global__ __launch_bounds__(256) void score_kernel(
    const float* __restrict__ hiT, const float* __restrict__ hjbT,
    const float* __restrict__ W2, const float* __restrict__ b2p,
    float* __restrict__ out) {
  __shared__ float his[32 * DIM];  // 16 KB
  __shared__ float hjs[32 * DIM];  // 16 KB

  const int t = threadIdx.x;
  const int tx = t & 15;   // j-group
  const int ty = t >> 4;   // i-group
  const int ibase = blockIdx.y * 128;
  const int jbase = blockIdx.x * 128;

  const int srow = t >> 5;          // 0..7   (staging row within 8-row band)
  const int scol = (t & 31) * 4;    // 0..124 (staging col, float4 granules)

  v2f acc[8][4];
#pragma unroll
  for (int ii = 0; ii < 8; ++ii)
#pragma unroll
    for (int jj = 0; jj < 4; ++jj) acc[ii][jj] = (v2f){0.f, 0.f};

  float4 bufA[4], bufB[4];
  // prefetch chunk 0
  {
    const int d0 = 0;
#pragma unroll
    for (int k = 0; k < 4; ++k) {
      const int row = d0 + srow + 8 * k;
      bufA[k] = *(const float4*)(hiT + row * NROWS + ibase + scol);
      bufB[k] = *(const float4*)(hjbT + row * NROWS + jbase + scol);
    }
  }

  for (int c = 0; c < 4; ++c) {
    const int d0 = c * 32;
    // commit staged regs -> LDS
#pragma unroll
    for (int k = 0; k < 4; ++k) {
      *(float4*)(his + (srow + 8 * k) * DIM + scol) = bufA[k];
      *(float4*)(hjs + (srow + 8 * k) * DIM + scol) = bufB[k];
    }
    __syncthreads();

    // prefetch next chunk (overlaps with compute below)
    if (c < 3) {
      const int dn = d0 + 32;
#pragma unroll
      for (int k = 0; k < 4; ++k) {
        const int row = dn + srow + 8 * k;
        bufA[k] = *(const float4*)(hiT + row * NROWS + ibase + scol);
        bufB[k] = *(const float4*)(hjbT + row * NROWS + jbase + scol);
      }
    }

#pragma unroll 4
    for (int d = 0; d < 32; ++d) {
      const float wv = W2[d0 + d];  // uniform
      const float* hp = his + d * DIM + ty * 8;
      const float* jp = hjs + d * DIM + tx * 8;
      const float4 h0 = *(const float4*)(hp);
      const float4 h1 = *(const float4*)(hp + 4);
      const float4 j0 = *(const float4*)(jp);
      const float4 j1 = *(const float4*)(jp + 4);
      const float hiv[8] = {h0.x, h0.y, h0.z, h0.w, h1.x, h1.y, h1.z, h1.w};
      const v2f hjv[4] = {{j0.x, j0.y}, {j0.z, j0.w}, {j1.x, j1.y}, {j1.z, j1.w}};
      const v2f wv2 = {wv, wv};
      const v2f zero = {0.f, 0.f};
#pragma unroll
      for (int ii = 0; ii < 8; ++ii) {
        const v2f hb = {hiv[ii], hiv[ii]};
#pragma unroll
        for (int jj = 0; jj < 4; ++jj) {
          v2f s = hb + hjv[jj];                       // v_pk_add_f32
          s = __builtin_elementwise_max(s, zero);     // v_pk_max_f32
          acc[ii][jj] = __builtin_elementwise_fma(s, wv2, acc[ii][jj]);  // v_pk_fma_f32
        }
      }
    }
    __syncthreads();
  }

  const float bias = *b2p;
#pragma unroll
  for (int ii = 0; ii < 8; ++ii) {
    const int i = ibase + ty * 8 + ii;
    float* o = out + (size_t)i * NROWS + jbase + tx * 8;
    float4 o0 = {acc[ii][0].x + bias, acc[ii][0].y + bias,
                 acc[ii][1].x + bias, acc[ii][1].y + bias};
    float4 o1 = {acc[ii][2].x + bias, acc[ii][2].y + bias,
                 acc[ii][3].x + bias, acc[ii][3].y + bias};
    *(float4*)o = o0;
    *(float4*)(o + 4) = o1;
  }
}

extern "C" void kernel_launch(void* const* d_in, const int* in_sizes, int n_in,
                              void* d_out, int out_size, void* d_ws, size_t ws_size,
                              hipStream_t stream) {
  const float* z_i = (const float*)d_in[0];
  const float* z_j = (const float*)d_in[1];
  const float* W1  = (const float*)d_in[2];
  const float* b1  = (const float*)d_in[3];
  const float* W2  = (const float*)d_in[4];
  const float* b2  = (const float*)d_in[5];
  float* out = (float*)d_out;

  float* hiT  = (float*)d_ws;               // [128][2048]
  float* hjbT = hiT + (size_t)DIM * NROWS;  // [128][2048]  (needs 2 MB of ws)

  prep_kernel<<<256, 256, 0, stream>>>(z_i, z_j, W1, b1, hiT, hjbT);
  score_kernel<<<dim3(16, 16), 256, 0, stream>>>(hiT, hjbT, W2, b2, out);
}

// Round 2
// 116.026 us; speedup vs baseline: 1.1515x; 1.1515x over previous
//
#include <hip/hip_runtime.h>

#define DIM 128
#define NROWS 2048

typedef float v2f __attribute__((ext_vector_type(2)));

// ---------------------------------------------------------------------------
// prep: hiT[d][n]  = sum_k z_i[n][k] * W1[k][d]            (d-major, transposed)
//       hjbT[d][m] = b1[d] + sum_k z_j[m][k] * W1[128+k][d]
// grid (32 row-tiles, 8 d-tiles, 2 sides) = 512 blocks x 256 threads.
// Block = 64 rows x 16 d. z staged TRANSPOSED+padded in LDS (conflict-free
// k-loop reads, coalesced stores); W1 tile in LDS (no global loads in k-loop).
// ---------------------------------------------------------------------------
__global__ __launch_bounds__(256) void prep_kernel(
    const float* __restrict__ z_i, const float* __restrict__ z_j,
    const float* __restrict__ W1, const float* __restrict__ b1,
    float* __restrict__ hiT, float* __restrict__ hjbT) {
  __shared__ float zsT[DIM * 65];   // [k][row], row-dim padded to 65 -> 33.3 KB
  __shared__ float wt[DIM * 16];    // [k][dlocal] -> 8 KB

  const int t = threadIdx.x;
  const int side = blockIdx.z;               // 0: hi, 1: hjb
  const int rowbase = blockIdx.x * 64;
  const int d0 = blockIdx.y * 16;
  const float* z = side ? z_j : z_i;
  const float* w = W1 + side * (DIM * DIM);

  // stage 64 z-rows, transposed into zsT[k][row]
#pragma unroll
  for (int jj = 0; jj < 8; ++jj) {
    const int idx = t + jj * 256;
    const int row = idx >> 5;              // 0..63
    const int kc = (idx & 31) * 4;         // 0..124
    const float4 v = *(const float4*)(z + (size_t)(rowbase + row) * DIM + kc);
    zsT[(kc + 0) * 65 + row] = v.x;
    zsT[(kc + 1) * 65 + row] = v.y;
    zsT[(kc + 2) * 65 + row] = v.z;
    zsT[(kc + 3) * 65 + row] = v.w;
  }
  // stage W1 tile [128k][16d]
#pragma unroll
  for (int jj = 0; jj < 2; ++jj) {
    const int idx = t + jj * 256;
    const int k = idx >> 2;
    const int c = (idx & 3) * 4;
    *(float4*)(wt + k * 16 + c) = *(const float4*)(w + k * DIM + d0 + c);
  }
  __syncthreads();

  const int r = t & 63;        // row within tile (wave-coalesced)
  const int dg = t >> 6;       // 0..3, wave-uniform: this wave's 4 d's
  v2f acc0 = {0.f, 0.f}, acc1 = {0.f, 0.f};

#pragma unroll 8
  for (int k = 0; k < DIM; ++k) {
    const float zv = zsT[k * 65 + r];                       // 2-way = free
    const float4 wv = *(const float4*)(wt + k * 16 + dg * 4);  // broadcast
    const v2f zv2 = {zv, zv};
    acc0 = __builtin_elementwise_fma((v2f){wv.x, wv.y}, zv2, acc0);
    acc1 = __builtin_elementwise_fma((v2f){wv.z, wv.w}, zv2, acc1);
  }

  float* dst = (side ? hjbT : hiT);
  const int dglobal = d0 + dg * 4;
  float bias[4] = {0.f, 0.f, 0.f, 0.f};
  if (side) {
#pragma unroll
    for (int q = 0; q < 4; ++q) bias[q] = b1[dglobal + q];
  }
  const float res[4] = {acc0.x, acc0.y, acc1.x, acc1.y};
#pragma unroll
  for (int q = 0; q < 4; ++q)
    dst[(size_t)(dglobal + q) * NROWS + rowbase + r] = res[q] + bias[q];
}

// ---------------------------------------------------------------------------
// main: out[i][j] = b2 + sum_d relu(hiT[d][i] + hjbT[d][j]) * W2[d]
// grid (32,32) = 1024 blocks (4/CU, 16 waves/CU), 256 threads, 64x64 tile,
// 4x4 micro-tile. d staged to LDS in chunks of 32, [d][row] layout,
// conflict-free reads/writes. Packed-fp32 over j (v_pk_add/max/fma_f32).
// ---------------------------------------------------------------------------
__global__ __launch_bounds__(256) void score_kernel(
    const float* __restrict__ hiT, const float* __restrict__ hjbT,
    const float* __restrict__ W2, const float* __restrict__ b2p,
    float* __restrict__ out) {
  __shared__ float his[32 * 64];  // 8 KB  [d][i]
  __shared__ float hjs[32 * 64];  // 8 KB  [d][j]

  const int t = threadIdx.x;
  const int tx = t & 15;   // j-group (4 cols)
  const int ty = t >> 4;   // i-group (4 rows)
  const int ibase = blockIdx.y * 64;
  const int jbase = blockIdx.x * 64;

  const int srow = t >> 4;          // 0..15 (staging d-row; +16 for 2nd half)
  const int scol = (t & 15) * 4;    // 0..60, bank-conflict-free (2-way)

  v2f acc[4][2];
#pragma unroll
  for (int ii = 0; ii < 4; ++ii)
#pragma unroll
    for (int jj = 0; jj < 2; ++jj) acc[ii][jj] = (v2f){0.f, 0.f};

  float4 bufA[2], bufB[2];
#pragma unroll
  for (int k = 0; k < 2; ++k) {
    const int row = srow + 16 * k;
    bufA[k] = *(const float4*)(hiT + (size_t)row * NROWS + ibase + scol);
    bufB[k] = *(const float4*)(hjbT + (size_t)row * NROWS + jbase + scol);
  }

  for (int c = 0; c < 4; ++c) {
    const int d0 = c * 32;
#pragma unroll
    for (int k = 0; k < 2; ++k) {
      *(float4*)(his + (srow + 16 * k) * 64 + scol) = bufA[k];
      *(float4*)(hjs + (srow + 16 * k) * 64 + scol) = bufB[k];
    }
    __syncthreads();

    if (c < 3) {
      const int dn = d0 + 32;
#pragma unroll
      for (int k = 0; k < 2; ++k) {
        const int row = dn + srow + 16 * k;
        bufA[k] = *(const float4*)(hiT + (size_t)row * NROWS + ibase + scol);
        bufB[k] = *(const float4*)(hjbT + (size_t)row * NROWS + jbase + scol);
      }
    }

#pragma unroll 4
    for (int d = 0; d < 32; ++d) {
      const float wv = W2[d0 + d];  // uniform scalar load
      const float4 hv = *(const float4*)(his + d * 64 + ty * 4);  // broadcast
      const float4 jv = *(const float4*)(hjs + d * 64 + tx * 4);  // 2-way free
      const float hi4[4] = {hv.x, hv.y, hv.z, hv.w};
      const v2f hjv[2] = {{jv.x, jv.y}, {jv.z, jv.w}};
      const v2f wv2 = {wv, wv};
      const v2f zero = {0.f, 0.f};
#pragma unroll
      for (int ii = 0; ii < 4; ++ii) {
        const v2f hb = {hi4[ii], hi4[ii]};
#pragma unroll
        for (int jj = 0; jj < 2; ++jj) {
          v2f s = hb + hjv[jj];                     // v_pk_add_f32
          s = __builtin_elementwise_max(s, zero);   // v_pk_max_f32
          acc[ii][jj] = __builtin_elementwise_fma(s, wv2, acc[ii][jj]);
        }
      }
    }
    __syncthreads();
  }

  const float bias = *b2p;
#pragma unroll
  for (int ii = 0; ii < 4; ++ii) {
    const int i = ibase + ty * 4 + ii;
    float* o = out + (size_t)i * NROWS + jbase + tx * 4;
    const float4 ov = {acc[ii][0].x + bias, acc[ii][0].y + bias,
                       acc[ii][1].x + bias, acc[ii][1].y + bias};
    *(float4*)o = ov;
  }
}

extern "C" void kernel_launch(void* const* d_in, const int* in_sizes, int n_in,
                              void* d_out, int out_size, void* d_ws, size_t ws_size,
                              hipStream_t stream) {
  const float* z_i = (const float*)d_in[0];
  const float* z_j = (const float*)d_in[1];
  const float* W1  = (const float*)d_in[2];
  const float* b1  = (const float*)d_in[3];
  const float* W2  = (const float*)d_in[4];
  const float* b2  = (const float*)d_in[5];
  float* out = (float*)d_out;

  float* hiT  = (float*)d_ws;               // [128][2048]
  float* hjbT = hiT + (size_t)DIM * NROWS;  // [128][2048]  (2 MB of ws)

  prep_kernel<<<dim3(32, 8, 2), 256, 0, stream>>>(z_i, z_j, W1, b1, hiT, hjbT);
  score_kernel<<<dim3(32, 32), 256, 0, stream>>>(hiT, hjbT, W2, b2, out);
}

// Round 3
// 106.246 us; speedup vs baseline: 1.2575x; 1.0921x over previous
//
#include <hip/hip_runtime.h>

#define DIM 128
#define NROWS 2048
#define NDP 64  // d-pairs

typedef float v2f __attribute__((ext_vector_type(2)));
typedef _Float16 h2 __attribute__((ext_vector_type(2)));

static __device__ __forceinline__ h2 u2h(unsigned u) { return __builtin_bit_cast(h2, u); }
static __device__ __forceinline__ unsigned h2u(h2 h) { return __builtin_bit_cast(unsigned, h); }

// ---------------------------------------------------------------------------
// prep: hi2T[dp][n] = half2( hi[2dp][n], hi[2dp+1][n] )   (f16 d-pair tables)
//       hj2T[dp][m] = half2 of hj + b1 folded
// where hi = z_i @ W1[:128], hj = z_j @ W1[128:].
// grid (256 row-tiles of 8, 2 sides) x 512 thr (8 waves). W-side (64 KB f32)
// staged in LDS; lane owns one d-pair; z row is wave-uniform (scalar loads).
// ---------------------------------------------------------------------------
__global__ __launch_bounds__(512) void prep_kernel(
    const float* __restrict__ z_i, const float* __restrict__ z_j,
    const float* __restrict__ W1, const float* __restrict__ b1,
    unsigned* __restrict__ hi2T, unsigned* __restrict__ hj2T) {
  __shared__ float wlds[DIM * DIM];  // [k][d], 64 KB

  const int t = threadIdx.x;
  const int side = blockIdx.y;
  const int rowbase = blockIdx.x * 8;
  const float* w = W1 + side * (DIM * DIM);

  // stage W-side: 16384 floats, coalesced float4
#pragma unroll
  for (int rep = 0; rep < 8; ++rep) {
    const int idx = rep * 512 + t;            // 0..4095 float4s
    *(float4*)(wlds + idx * 4) = *(const float4*)(w + idx * 4);
  }
  __syncthreads();

  const int row = rowbase + (t >> 6);  // wave-uniform
  const int dp = t & 63;
  const float* zrow = (side ? z_j : z_i) + (size_t)row * DIM;

  v2f acc = {0.f, 0.f};
#pragma unroll 8
  for (int k = 0; k < DIM; ++k) {
    const float zv = zrow[k];                                   // uniform
    const v2f wv = *(const v2f*)(wlds + k * DIM + dp * 2);      // ds_read_b64
    acc = __builtin_elementwise_fma(wv, (v2f){zv, zv}, acc);
  }

  if (side) {
    acc.x += b1[2 * dp];
    acc.y += b1[2 * dp + 1];
  }
  h2 hv = {(_Float16)acc.x, (_Float16)acc.y};
  unsigned* dst = side ? hj2T : hi2T;
  dst[(size_t)dp * NROWS + row] = h2u(hv);
}

// ---------------------------------------------------------------------------
// score: out[i][j] = b2 + sum_dp dot2( relu(hi2[dp][i] + hj2[dp][j]), w2[dp] )
// grid (16 j-tiles, 32 i-tiles) = 512 blocks x 256 thr. Tile 64i x 128j,
// micro 4i x 8j. ALL 128 d staged once (48 KB LDS), ONE barrier, then a
// barrier-free dp loop: v_pk_add_f16 + v_pk_max_f16 + v_dot2_f32_f16.
// ---------------------------------------------------------------------------
__global__ __launch_bounds__(256) void score_kernel(
    const unsigned* __restrict__ hi2T, const unsigned* __restrict__ hj2T,
    const float* __restrict__ W2, const float* __restrict__ b2p,
    float* __restrict__ out) {
  __shared__ unsigned his2[NDP * 64];    // 16 KB  [dp][i]
  __shared__ unsigned hjs2[NDP * 128];   // 32 KB  [dp][j]
  __shared__ unsigned w2s[NDP];          // 256 B

  const int t = threadIdx.x;
  const int ibase = blockIdx.y * 64;
  const int jbase = blockIdx.x * 128;

  // stage hi tile: 4096 uints
#pragma unroll
  for (int rep = 0; rep < 4; ++rep) {
    const int idx = rep * 256 + t;
    const int dp = idx >> 4, c = (idx & 15) * 4;
    *(uint4*)(his2 + dp * 64 + c) =
        *(const uint4*)(hi2T + (size_t)dp * NROWS + ibase + c);
  }
  // stage hj tile: 8192 uints
#pragma unroll
  for (int rep = 0; rep < 8; ++rep) {
    const int idx = rep * 256 + t;
    const int dp = idx >> 5, c = (idx & 31) * 4;
    *(uint4*)(hjs2 + dp * 128 + c) =
        *(const uint4*)(hj2T + (size_t)dp * NROWS + jbase + c);
  }
  if (t < NDP) {
    h2 wp = {(_Float16)W2[2 * t], (_Float16)W2[2 * t + 1]};
    w2s[t] = h2u(wp);
  }
  __syncthreads();  // the only barrier

  const int tx = t & 15;   // j-group: 8 j's
  const int ty = t >> 4;   // i-group: 4 i's

  float acc[4][8];
#pragma unroll
  for (int ii = 0; ii < 4; ++ii)
#pragma unroll
    for (int jj = 0; jj < 8; ++jj) acc[ii][jj] = 0.f;

#pragma unroll 8
  for (int dp = 0; dp < NDP; ++dp) {
    const uint4 hu = *(const uint4*)(his2 + dp * 64 + ty * 4);       // 4 i-pairs
    const uint4 ju0 = *(const uint4*)(hjs2 + dp * 128 + tx * 8);     // 4 j-pairs
    const uint4 ju1 = *(const uint4*)(hjs2 + dp * 128 + tx * 8 + 4); // 4 more
    const h2 wp = u2h(w2s[dp]);                                      // broadcast
    const h2 hiv[4] = {u2h(hu.x), u2h(hu.y), u2h(hu.z), u2h(hu.w)};
    const h2 hjv[8] = {u2h(ju0.x), u2h(ju0.y), u2h(ju0.z), u2h(ju0.w),
                       u2h(ju1.x), u2h(ju1.y), u2h(ju1.z), u2h(ju1.w)};
    const h2 zero = {(_Float16)0.f, (_Float16)0.f};
#pragma unroll
    for (int ii = 0; ii < 4; ++ii) {
#pragma unroll
      for (int jj = 0; jj < 8; ++jj) {
        h2 s = hiv[ii] + hjv[jj];                  // v_pk_add_f16
        s = __builtin_elementwise_max(s, zero);    // v_pk_max_f16
        acc[ii][jj] = __builtin_amdgcn_fdot2(s, wp, acc[ii][jj], false);
      }
    }
  }

  const float bias = *b2p;
#pragma unroll
  for (int ii = 0; ii < 4; ++ii) {
    const int i = ibase + ty * 4 + ii;
    float* o = out + (size_t)i * NROWS + jbase + tx * 8;
    const float4 o0 = {acc[ii][0] + bias, acc[ii][1] + bias,
                       acc[ii][2] + bias, acc[ii][3] + bias};
    const float4 o1 = {acc[ii][4] + bias, acc[ii][5] + bias,
                       acc[ii][6] + bias, acc[ii][7] + bias};
    *(float4*)o = o0;
    *(float4*)(o + 4) = o1;
  }
}

extern "C" void kernel_launch(void* const* d_in, const int* in_sizes, int n_in,
                              void* d_out, int out_size, void* d_ws, size_t ws_size,
                              hipStream_t stream) {
  const float* z_i = (const float*)d_in[0];
  const float* z_j = (const float*)d_in[1];
  const float* W1  = (const float*)d_in[2];
  const float* b1  = (const float*)d_in[3];
  const float* W2  = (const float*)d_in[4];
  const float* b2  = (const float*)d_in[5];
  float* out = (float*)d_out;

  unsigned* hi2T = (unsigned*)d_ws;                  // [64][2048] half2 -> 512 KB
  unsigned* hj2T = hi2T + (size_t)NDP * NROWS;       // [64][2048] half2 -> 512 KB

  prep_kernel<<<dim3(256, 2), 512, 0, stream>>>(z_i, z_j, W1, b1, hi2T, hj2T);
  score_kernel<<<dim3(16, 32), 256, 0, stream>>>(hi2T, hj2T, W2, b2, out);
}

// Round 4
// 105.341 us; speedup vs baseline: 1.2683x; 1.0086x over previous
//
#include <hip/hip_runtime.h>

#define DIM 128
#define NROWS 2048
#define NDP 64  // d-pairs

typedef float v2f __attribute__((ext_vector_type(2)));
typedef _Float16 h2 __attribute__((ext_vector_type(2)));

static __device__ __forceinline__ h2 u2h(unsigned u) { return __builtin_bit_cast(h2, u); }
static __device__ __forceinline__ unsigned h2u(h2 h) { return __builtin_bit_cast(unsigned, h); }

// ---------------------------------------------------------------------------
// prep: hi2T[dp][n] = half2( hi[2dp][n], hi[2dp+1][n] ),  hj2T likewise + b1.
// grid (256 row-tiles of 8, 2 sides) x 256 thr. z rows staged in 4 KB LDS
// (whole-wave broadcast reads); W1 column-pair read from global (coalesced
// 8 B/lane, L2-resident); thread = 1 d-pair x 2 rows -> 1 load : 2 pk-fma.
// ---------------------------------------------------------------------------
__global__ __launch_bounds__(256) void prep_kernel(
    const float* __restrict__ z_i, const float* __restrict__ z_j,
    const float* __restrict__ W1, const float* __restrict__ b1,
    unsigned* __restrict__ hi2T, unsigned* __restrict__ hj2T) {
  __shared__ float zs[8 * DIM];  // 4 KB

  const int t = threadIdx.x;
  const int side = blockIdx.y;
  const int rowbase = blockIdx.x * 8;

  // stage 8 z rows (1024 floats), coalesced
  const float* z = (side ? z_j : z_i) + (size_t)rowbase * DIM;
  ((float4*)zs)[t] = ((const float4*)z)[t];
  __syncthreads();

  const int dp = t & 63;       // d-pair
  const int rg = t >> 6;       // row-group: rows rg*2, rg*2+1
  const float* wcol = W1 + side * (DIM * DIM) + dp * 2;
  const float* z0 = zs + (rg * 2) * DIM;
  const float* z1 = z0 + DIM;

  v2f acc0 = {0.f, 0.f}, acc1 = {0.f, 0.f};
#pragma unroll 8
  for (int k = 0; k < DIM; ++k) {
    const v2f wv = *(const v2f*)(wcol + (size_t)k * DIM);  // coalesced 8 B/lane
    const float a = z0[k], b = z1[k];                      // LDS broadcast
    acc0 = __builtin_elementwise_fma(wv, (v2f){a, a}, acc0);
    acc1 = __builtin_elementwise_fma(wv, (v2f){b, b}, acc1);
  }

  if (side) {
    const v2f bb = *(const v2f*)(b1 + dp * 2);
    acc0 += bb;
    acc1 += bb;
  }
  unsigned* dst = (side ? hj2T : hi2T) + (size_t)dp * NROWS + rowbase + rg * 2;
  dst[0] = h2u((h2){(_Float16)acc0.x, (_Float16)acc0.y});
  dst[1] = h2u((h2){(_Float16)acc1.x, (_Float16)acc1.y});
}

// ---------------------------------------------------------------------------
// score: out[i][j] = b2 + sum_dp dot2( relu(hi2[dp][i] + hj2[dp][j]), w2[dp] )
// grid (32,32) = 1024 blocks = EXACTLY 4/CU co-resident (32.25 KB LDS),
// __launch_bounds__(256,4) caps VGPR<=128 for 16 waves/CU. Tile 64x64,
// micro 4i x 4j: all LDS reads 16B-stride uint4 -> conflict-free.
// Core: v_pk_add_f16 + v_pk_max_f16 + v_dot2_f32_f16 (1.5 instr/elem).
// ---------------------------------------------------------------------------
__global__ __launch_bounds__(256, 4) void score_kernel(
    const unsigned* __restrict__ hi2T, const unsigned* __restrict__ hj2T,
    const float* __restrict__ W2, const float* __restrict__ b2p,
    float* __restrict__ out) {
  __shared__ unsigned his2[NDP * 64];  // 16 KB  [dp][i]
  __shared__ unsigned hjs2[NDP * 64];  // 16 KB  [dp][j]
  __shared__ unsigned w2s[NDP];        // 256 B

  const int t = threadIdx.x;
  const int ibase = blockIdx.y * 64;
  const int jbase = blockIdx.x * 64;
  const float bias = *b2p;

  // stage tiles: 4096 uints each, coalesced 256 B per 16 lanes
#pragma unroll
  for (int rep = 0; rep < 4; ++rep) {
    const int idx = rep * 256 + t;
    const int dp = idx >> 4, c = (idx & 15) * 4;
    *(uint4*)(his2 + dp * 64 + c) =
        *(const uint4*)(hi2T + (size_t)dp * NROWS + ibase + c);
    *(uint4*)(hjs2 + dp * 64 + c) =
        *(const uint4*)(hj2T + (size_t)dp * NROWS + jbase + c);
  }
  if (t < NDP) {
    const v2f wp = *(const v2f*)(W2 + t * 2);
    w2s[t] = h2u((h2){(_Float16)wp.x, (_Float16)wp.y});
  }
  __syncthreads();  // the only barrier

  const int tx = t & 15;   // j-group: 4 j's
  const int ty = t >> 4;   // i-group: 4 i's

  float acc[4][4];
#pragma unroll
  for (int ii = 0; ii < 4; ++ii)
#pragma unroll
    for (int jj = 0; jj < 4; ++jj) acc[ii][jj] = 0.f;

  const h2 zero = {(_Float16)0.f, (_Float16)0.f};
#pragma unroll 2
  for (int dpg = 0; dpg < 16; ++dpg) {
    const uint4 w4 = *(const uint4*)(w2s + dpg * 4);  // broadcast
    const h2 wp[4] = {u2h(w4.x), u2h(w4.y), u2h(w4.z), u2h(w4.w)};
#pragma unroll
    for (int q = 0; q < 4; ++q) {
      const int dp = dpg * 4 + q;
      const uint4 hu = *(const uint4*)(his2 + dp * 64 + ty * 4);  // 2-way free
      const uint4 ju = *(const uint4*)(hjs2 + dp * 64 + tx * 4);  // 2-way free
      const h2 hiv[4] = {u2h(hu.x), u2h(hu.y), u2h(hu.z), u2h(hu.w)};
      const h2 hjv[4] = {u2h(ju.x), u2h(ju.y), u2h(ju.z), u2h(ju.w)};
#pragma unroll
      for (int ii = 0; ii < 4; ++ii) {
#pragma unroll
        for (int jj = 0; jj < 4; ++jj) {
          h2 s = hiv[ii] + hjv[jj];                  // v_pk_add_f16
          s = __builtin_elementwise_max(s, zero);    // v_pk_max_f16
          acc[ii][jj] = __builtin_amdgcn_fdot2(s, wp[q], acc[ii][jj], false);
        }
      }
    }
  }

#pragma unroll
  for (int ii = 0; ii < 4; ++ii) {
    const int i = ibase + ty * 4 + ii;
    float* o = out + (size_t)i * NROWS + jbase + tx * 4;
    const float4 ov = {acc[ii][0] + bias, acc[ii][1] + bias,
                       acc[ii][2] + bias, acc[ii][3] + bias};
    *(float4*)o = ov;  // 16 lanes x 16 B contiguous per row
  }
}

extern "C" void kernel_launch(void* const* d_in, const int* in_sizes, int n_in,
                              void* d_out, int out_size, void* d_ws, size_t ws_size,
                              hipStream_t stream) {
  const float* z_i = (const float*)d_in[0];
  const float* z_j = (const float*)d_in[1];
  const float* W1  = (const float*)d_in[2];
  const float* b1  = (const float*)d_in[3];
  const float* W2  = (const float*)d_in[4];
  const float* b2  = (const float*)d_in[5];
  float* out = (float*)d_out;

  unsigned* hi2T = (unsigned*)d_ws;             // [64][2048] half2 -> 512 KB
  unsigned* hj2T = hi2T + (size_t)NDP * NROWS;  // [64][2048] half2 -> 512 KB

  prep_kernel<<<dim3(256, 2), 256, 0, stream>>>(z_i, z_j, W1, b1, hi2T, hj2T);
  score_kernel<<<dim3(32, 32), 256, 0, stream>>>(hi2T, hj2T, W2, b2, out);
}